// Round 1
// baseline (484.193 us; speedup 1.0000x reference)
//
#include <hip/hip_runtime.h>
#include <stdint.h>

#define N_B 8
#define A_N 131072
#define T_N 64
#define NUM_TRAIN 256
#define POS_CAP 65536
#define NEG_CAP 32768
#define NEG_TAU 0.05f
#define NB 2048
#define ITEM_CAP 1024

typedef unsigned long long u64;
typedef unsigned int u32;

// ---------------- init: zero counters, init column-argmax packed values ----------------
// colpack init = pack(iou=0, anchor=0) = (0<<32) | ~0u  -> all-zero column falls back to anchor 0,
// matching jnp.argmax's first-index semantics.
__global__ void k_init(u64* colpack, int* cnts) {
    int i = blockIdx.x * blockDim.x + threadIdx.x;
    if (i < N_B * T_N) colpack[i] = 0xFFFFFFFFull;
    if (i < 2 * N_B)   cnts[i] = 0;
}

// IoU exactly matching the reference op sequence (no FMA contraction).
__device__ __forceinline__ float iou_one(float ay1, float ax1, float ay2, float ax2, float a_area,
                                         float gy1, float gx1, float gy2, float gx2) {
#pragma clang fp contract(off)
    float g_area = (gy2 - gy1) * (gx2 - gx1);
    float ih = fmaxf(fminf(ay2, gy2) - fmaxf(ay1, gy1), 0.0f);
    float iw = fmaxf(fminf(ax2, gx2) - fmaxf(ax1, gx1), 0.0f);
    float inter = ih * iw;
    float uni = (a_area + g_area) - inter;
    return uni > 0.0f ? inter / uni : 0.0f;
}

// ---------------- main: per-anchor row max/argmax + per-gt column argmax ----------------
__global__ void k_main(const float* __restrict__ anchors, const float* __restrict__ gts,
                       float* __restrict__ iou_max, int* __restrict__ best_gt,
                       u64* __restrict__ colpack) {
    __shared__ float gy1s[T_N], gx1s[T_N], gy2s[T_N], gx2s[T_N];
    __shared__ u64 cmax[T_N];
    int n = blockIdx.y;
    int tid = threadIdx.x;
    int a = blockIdx.x * 256 + tid;

    {   // SoA gt tile: T*4 = 256 floats, one per thread
        float v = gts[n * T_N * 4 + tid];
        int t = tid >> 2, c = tid & 3;
        if (c == 0) gy1s[t] = v; else if (c == 1) gx1s[t] = v;
        else if (c == 2) gy2s[t] = v; else gx2s[t] = v;
    }
    if (tid < T_N) cmax[tid] = 0xFFFFFFFFull;  // pack(0, ~0) -> anchor 0 fallback
    __syncthreads();

    float4 ab = reinterpret_cast<const float4*>(anchors)[(size_t)n * A_N + a];
    float ay1 = ab.x, ax1 = ab.y, ay2 = ab.z, ax2 = ab.w;
    bool inb = (ay1 >= 0.f) && (ax1 >= 0.f) && (ay2 <= 1.f) && (ax2 <= 1.f);
    if (!inb) { ay1 = ax1 = ay2 = ax2 = 0.f; }
    float a_area;
    {
#pragma clang fp contract(off)
        a_area = (ay2 - ay1) * (ax2 - ax1);
    }

    u64 rowp = 0xFFFFFFFFull;  // pack(0, ~0) -> t=0 fallback (first-max semantics)
    u32 ia = ~(u32)a;
    int lane = tid & 63;
#pragma unroll 4
    for (int j = 0; j < T_N; j++) {
        int t = (lane + j) & (T_N - 1);  // lane-staggered: 64 distinct t per wave
        float v = iou_one(ay1, ax1, ay2, ax2, a_area, gy1s[t], gx1s[t], gy2s[t], gx2s[t]);
        u64 pr = ((u64)__float_as_uint(v) << 32) | (u32)(~(u32)t);
        rowp = pr > rowp ? pr : rowp;
        if (v > 0.0f) {  // zero entries can never beat the pack(0, anchor 0) init
            u64 pc = ((u64)__float_as_uint(v) << 32) | ia;
            atomicMax(&cmax[t], pc);
        }
    }
    size_t gi = (size_t)n * A_N + a;
    iou_max[gi] = __uint_as_float((u32)(rowp >> 32));
    best_gt[gi] = (int)(~(u32)(rowp & 0xFFFFFFFFu));
    __syncthreads();
    if (tid < T_N) atomicMax(&colpack[n * T_N + tid], cmax[tid]);
}

// ---------------- classify + gather candidate lists ----------------
__global__ void k_classify(const float* __restrict__ iou_max, const u64* __restrict__ colpack,
                           const float* __restrict__ rpos, const float* __restrict__ rneg,
                           int* __restrict__ class_tmp,
                           u64* __restrict__ pos_list, u64* __restrict__ neg_list,
                           int* __restrict__ cnts) {
    __shared__ int ba[T_N];
    int n = blockIdx.y;
    int tid = threadIdx.x;
    int a = blockIdx.x * 256 + tid;
    if (tid < T_N) ba[tid] = (int)(~(u32)(colpack[n * T_N + tid] & 0xFFFFFFFFull));
    __syncthreads();

    size_t gi = (size_t)n * A_N + a;
    float im = iou_max[gi];
    int c = -1;
    if (im < 0.3f) c = 0;
    bool isbest = false;
#pragma unroll
    for (int t = 0; t < T_N; t++) isbest |= (ba[t] == a);
    if (isbest) c = 1;
    if (im >= 0.7f) c = 1;
    class_tmp[gi] = c;

    if (c == 1) {
        u64 p = ((u64)__float_as_uint(rpos[gi]) << 32) | (u32)a;
        int i = atomicAdd(&cnts[n], 1);
        if (i < POS_CAP) pos_list[n * POS_CAP + i] = p;
    } else if (c == 0) {
        float r = rneg[gi];
        if (r < NEG_TAU) {
            u64 p = ((u64)__float_as_uint(r) << 32) | (u32)a;
            int i = atomicAdd(&cnts[N_B + n], 1);
            if (i < NEG_CAP) neg_list[n * NEG_CAP + i] = p;
        }
    }
}

// ---------------- exact k-th smallest packed value (block-cooperative) ----------------
__device__ u64 select_kth(const u64* list, int cnt, int k, float scale, u64 overflow_cutoff,
                          int* hist, int* csum, u64* items, int* misc, u64* result) {
    int tid = threadIdx.x;
    if (k >= cnt) return overflow_cutoff;  // uniform

    for (int i = tid; i < NB; i += 256) hist[i] = 0;
    if (tid == 0) { misc[0] = -1; misc[1] = 0; misc[2] = 0; *result = overflow_cutoff; }
    __syncthreads();

    for (int i = tid; i < cnt; i += 256) {
        float v = __uint_as_float((u32)(list[i] >> 32));
        int b = (int)(v * scale); b = b < NB - 1 ? b : NB - 1;
        atomicAdd(&hist[b], 1);
    }
    __syncthreads();

    int base = tid * (NB / 256);
    int s = 0;
#pragma unroll
    for (int j = 0; j < NB / 256; j++) s += hist[base + j];
    csum[tid] = s;
    __syncthreads();
    if (tid == 0) {
        int run = 0;
        for (int j = 0; j < 256; j++) { int t = csum[j]; csum[j] = run; run += t; }
    }
    __syncthreads();
    int run = csum[tid];
#pragma unroll
    for (int j = 0; j < NB / 256; j++) {
        int h = hist[base + j];
        if (k >= run && k < run + h) { misc[0] = base + j; misc[1] = run; }
        run += h;
    }
    __syncthreads();
    int b = misc[0], before = misc[1];

    for (int i = tid; i < cnt; i += 256) {
        u64 p = list[i];
        float v = __uint_as_float((u32)(p >> 32));
        int bb = (int)(v * scale); bb = bb < NB - 1 ? bb : NB - 1;
        if (bb == b) { int ix = atomicAdd(&misc[2], 1); if (ix < ITEM_CAP) items[ix] = p; }
    }
    __syncthreads();
    int m = misc[2]; m = m < ITEM_CAP ? m : ITEM_CAP;
    int target = k - before;
    for (int i = tid; i < m; i += 256) {
        u64 p = items[i];
        int r = 0;
        for (int j = 0; j < m; j++) r += (items[j] < p);
        if (r == target) *result = p;
    }
    __syncthreads();
    u64 res = *result;
    __syncthreads();
    return res;
}

__global__ void k_select(const u64* __restrict__ pos_list, const u64* __restrict__ neg_list,
                         const int* __restrict__ cnts, u64* __restrict__ cutoff) {
    __shared__ int hist[NB];
    __shared__ int csum[256];
    __shared__ u64 items[ITEM_CAP];
    __shared__ int misc[4];
    __shared__ u64 result;
    int n = blockIdx.x;
    int P = cnts[n];
    int C = cnts[N_B + n];
    int Pc = P < POS_CAP ? P : POS_CAP;
    int Cc = C < NEG_CAP ? C : NEG_CAP;

    u64 cpos = select_kth(pos_list + n * POS_CAP, Pc, NUM_TRAIN / 2, (float)NB,
                          0xFFFFFFFFFFFFFFFFull, hist, csum, items, misc, &result);
    int n_pos = P < NUM_TRAIN / 2 ? P : NUM_TRAIN / 2;
    int k_neg = NUM_TRAIN - n_pos;
    u64 cneg = select_kth(neg_list + n * NEG_CAP, Cc, k_neg, (float)NB / NEG_TAU,
                          ((u64)__float_as_uint(NEG_TAU) << 32), hist, csum, items, misc, &result);
    if (threadIdx.x == 0) { cutoff[2 * n] = cpos; cutoff[2 * n + 1] = cneg; }
}

// ---------------- final: subsample decision + deltas + output ----------------
__global__ void k_final(const float* __restrict__ anchors, const float* __restrict__ gts,
                        const int* __restrict__ class_tmp, const int* __restrict__ best_gt,
                        const float* __restrict__ rpos, const float* __restrict__ rneg,
                        const u64* __restrict__ cutoff,
                        float* __restrict__ out_classes, float4* __restrict__ out_deltas) {
    __shared__ float g[T_N * 4];
    int n = blockIdx.y;
    int tid = threadIdx.x;
    int a = blockIdx.x * 256 + tid;
    g[tid] = gts[n * T_N * 4 + tid];
    __syncthreads();

    size_t gi = (size_t)n * A_N + a;
    int c = class_tmp[gi];
    int fc = -1;
    if (c == 1) {
        u64 p = ((u64)__float_as_uint(rpos[gi]) << 32) | (u32)a;
        fc = (p < cutoff[2 * n]) ? 1 : -1;
    } else if (c == 0) {
        u64 p = ((u64)__float_as_uint(rneg[gi]) << 32) | (u32)a;
        fc = (p < cutoff[2 * n + 1]) ? 0 : -1;
    }
    out_classes[gi] = (float)fc;

    float4 d = make_float4(0.f, 0.f, 0.f, 0.f);
    if (fc == 1) {
        float4 ab = reinterpret_cast<const float4*>(anchors)[gi];
        float ay1 = ab.x, ax1 = ab.y, ay2 = ab.z, ax2 = ab.w;
        bool inb = (ay1 >= 0.f) && (ax1 >= 0.f) && (ay2 <= 1.f) && (ax2 <= 1.f);
        if (!inb) { ay1 = ax1 = ay2 = ax2 = 0.f; }
        int bg = best_gt[gi];
        float gy1 = g[bg * 4 + 0], gx1 = g[bg * 4 + 1], gy2 = g[bg * 4 + 2], gx2 = g[bg * 4 + 3];
        float ah = ay2 - ay1, aw = ax2 - ax1;
        float acy = ay1 + 0.5f * ah, acx = ax1 + 0.5f * aw;
        float gh = gy2 - gy1, gw = gx2 - gx1;
        float gcy = gy1 + 0.5f * gh, gcx = gx1 + 0.5f * gw;
        float ah_s = ah > 0.f ? ah : 1.f, aw_s = aw > 0.f ? aw : 1.f;
        float gh_s = gh > 0.f ? gh : 1.f, gw_s = gw > 0.f ? gw : 1.f;
        d.x = (gcy - acy) / ah_s;
        d.y = (gcx - acx) / aw_s;
        d.z = logf(gh_s / ah_s);
        d.w = logf(gw_s / aw_s);
    }
    out_deltas[gi] = d;
}

extern "C" void kernel_launch(void* const* d_in, const int* in_sizes, int n_in,
                              void* d_out, int out_size, void* d_ws, size_t ws_size,
                              hipStream_t stream) {
    const float* anchors = (const float*)d_in[0];
    const float* gts     = (const float*)d_in[1];
    const float* rpos    = (const float*)d_in[2];
    const float* rneg    = (const float*)d_in[3];

    char* p = (char*)d_ws;
    u64* cutoff   = (u64*)p;  p += 2 * N_B * sizeof(u64);
    u64* colpack  = (u64*)p;  p += N_B * T_N * sizeof(u64);
    u64* pos_list = (u64*)p;  p += (size_t)N_B * POS_CAP * sizeof(u64);
    u64* neg_list = (u64*)p;  p += (size_t)N_B * NEG_CAP * sizeof(u64);
    float* iou_max = (float*)p; p += (size_t)N_B * A_N * sizeof(float);
    int* best_gt   = (int*)p;   p += (size_t)N_B * A_N * sizeof(int);
    int* class_tmp = (int*)p;   p += (size_t)N_B * A_N * sizeof(int);
    int* cnts      = (int*)p;   p += 2 * N_B * sizeof(int);

    float* out_classes = (float*)d_out;
    float4* out_deltas = (float4*)(out_classes + (size_t)N_B * A_N);

    dim3 grid(A_N / 256, N_B);
    k_init<<<2, 256, 0, stream>>>(colpack, cnts);
    k_main<<<grid, 256, 0, stream>>>(anchors, gts, iou_max, best_gt, colpack);
    k_classify<<<grid, 256, 0, stream>>>(iou_max, colpack, rpos, rneg,
                                         class_tmp, pos_list, neg_list, cnts);
    k_select<<<N_B, 256, 0, stream>>>(pos_list, neg_list, cnts, cutoff);
    k_final<<<grid, 256, 0, stream>>>(anchors, gts, class_tmp, best_gt, rpos, rneg,
                                      cutoff, out_classes, out_deltas);
}